// Round 15
// baseline (130.817 us; speedup 1.0000x reference)
//
#include <hip/hip_runtime.h>

// Problem shape (fixed by reference): N=64, C=1024, H=W=28 -> HW=784
#define HWD 784
#define Q4  196            // HWD/4 float4 slots per channel row
#define CD  1024
#define ND  64

#define CHPB 32            // channels per pass1 block (4 waves x 8)
#define NCHUNK (CD / CHPB) // 32 partial chunks

typedef float f32x4 __attribute__((ext_vector_type(4)));

__device__ __forceinline__ float4 cam4(float4 v, float wc) {
    float4 r;
    r.x = fmaxf(v.x * wc, 0.f);
    r.y = fmaxf(v.y * wc, 0.f);
    r.z = fmaxf(v.z * wc, 0.f);
    r.w = fmaxf(v.w * wc, 0.f);
    return r;
}
__device__ __forceinline__ float max4(float4 v) {
    return fmaxf(fmaxf(v.x, v.y), fmaxf(v.z, v.w));
}
__device__ __forceinline__ void accdrop(float4& a, float4 c, float thr) {
    a.x += (c.x > thr) ? 0.f : c.x;
    a.y += (c.y > thr) ? 0.f : c.y;
    a.z += (c.z > thr) ? 0.f : c.z;
    a.w += (c.w > thr) ? 0.f : c.w;
}

// ---------------------------------------------------------------------------
// Pass 1 (round-14 v6, unchanged): 2-deep software pipeline, LDS combine.
// MEASUREMENT ROUND: launched TWICE (idempotent) — the total-time delta vs
// the 98.85us single-launch baseline equals one L3-warm pass1 execution.
// ---------------------------------------------------------------------------
__global__ void __launch_bounds__(256) pass1_kernel(const float* __restrict__ x,
                                                    const float* __restrict__ w,
                                                    const float* __restrict__ mu_p,
                                                    float* __restrict__ Spart) {
    __shared__ float4 drp[4][197];   // wave stride 197*4 = 788 floats

    const int t = threadIdx.x;
    const int wave = t >> 6;
    const int lane = t & 63;
    const int n = blockIdx.y;
    const int cbase = blockIdx.x * CHPB + wave * 8;
    const float mu = mu_p[0];

    const float4* rows = reinterpret_cast<const float4*>(x + ((size_t)n * CD + cbase) * HWD);

    float4 acc0 = {0.f,0.f,0.f,0.f}, acc1 = {0.f,0.f,0.f,0.f};
    float4 acc2 = {0.f,0.f,0.f,0.f}, acc3 = {0.f,0.f,0.f,0.f};

    // prologue: load channel 0
    float4 v0 = rows[lane];
    float4 v1 = rows[lane + 64];
    float4 v2 = rows[lane + 128];
    float4 v3 = (lane < 4) ? rows[192 + lane] : float4{0.f,0.f,0.f,0.f};

    #pragma unroll 2
    for (int j = 0; j < 8; ++j) {
        // prefetch channel j+1 (independent of this iteration's compute)
        float4 p0 = v0, p1 = v1, p2 = v2, p3 = v3;
        if (j < 7) {
            const float4* rn = rows + (j + 1) * Q4;
            p0 = rn[lane];
            p1 = rn[lane + 64];
            p2 = rn[lane + 128];
            if (lane < 4) p3 = rn[192 + lane];
        }

        const float wc = w[cbase + j];
        float4 c0 = cam4(v0, wc), c1 = cam4(v1, wc);
        float4 c2 = cam4(v2, wc), c3 = cam4(v3, wc);

        float m = fmaxf(fmaxf(max4(c0), max4(c1)), fmaxf(max4(c2), max4(c3)));
        #pragma unroll
        for (int off = 32; off > 0; off >>= 1)
            m = fmaxf(m, __shfl_xor(m, off, 64));
        const float thr = m * mu;

        accdrop(acc0, c0, thr);
        accdrop(acc1, c1, thr);
        accdrop(acc2, c2, thr);
        accdrop(acc3, c3, thr);      // zeros for lane >= 4: harmless

        v0 = p0; v1 = p1; v2 = p2; v3 = p3;
    }

    drp[wave][lane]       = acc0;
    drp[wave][64 + lane]  = acc1;
    drp[wave][128 + lane] = acc2;
    if (lane < 4) drp[wave][192 + lane] = acc3;
    __syncthreads();

    const float* f = reinterpret_cast<const float*>(&drp[0][0]);
    float* sp = Spart + ((size_t)blockIdx.x * ND + n) * HWD;
    for (int p = t; p < HWD; p += 256)
        sp[p] = f[p] + f[788 + p] + f[2 * 788 + p] + f[3 * 788 + p];
}

// ---------------------------------------------------------------------------
// Reduce: S[n,p] = sum over 32 chunks of Spart[chunk][n][p]. Coalesced.
// ---------------------------------------------------------------------------
__global__ void __launch_bounds__(256) reduce_kernel(const float* __restrict__ Spart,
                                                     float* __restrict__ S) {
    const int j = blockIdx.x * 256 + threadIdx.x;   // 0 .. 50175
    float s = 0.f;
    #pragma unroll
    for (int ch = 0; ch < NCHUNK; ++ch)
        s += Spart[(size_t)ch * ND * HWD + j];
    S[j] = s;
}

// ---------------------------------------------------------------------------
// Mult (round-14, unchanged): fixed (n,p4) per thread, S loaded once,
// 1KB/wave linear segments, NT stores.
// ---------------------------------------------------------------------------
__global__ void __launch_bounds__(256) mult_kernel(const float* __restrict__ x,
                                                   const float* __restrict__ S,
                                                   float* __restrict__ out) {
    const float4* x4 = reinterpret_cast<const float4*>(x);
    const float4* S4 = reinterpret_cast<const float4*>(S);

    const int tid = blockIdx.x * 256 + threadIdx.x;   // 0 .. 802815
    const int n   = tid / (64 * Q4);                  // 0..63
    const int rem = tid - n * (64 * Q4);
    const int c0  = rem / Q4;                         // 0..63
    const int p4  = rem - c0 * Q4;                    // 0..195

    const float4 sv = S4[n * Q4 + p4];                // one S load, reused 16x
    size_t i4 = ((size_t)(n * CD + c0)) * Q4 + p4;

    #pragma unroll 8
    for (int k = 0; k < 16; ++k, i4 += (size_t)64 * Q4) {
        float4 xv = x4[i4];
        float4 o;
        o.x = xv.x * sv.x;
        o.y = xv.y * sv.y;
        o.z = xv.z * sv.z;
        o.w = xv.w * sv.w;
        __builtin_nontemporal_store(*reinterpret_cast<const f32x4*>(&o),
                                    reinterpret_cast<f32x4*>(out) + i4);
    }
}

extern "C" void kernel_launch(void* const* d_in, const int* in_sizes, int n_in,
                              void* d_out, int out_size, void* d_ws, size_t ws_size,
                              hipStream_t stream) {
    const float* x  = (const float*)d_in[0];   // [N, C, H, W] f32
    const float* w  = (const float*)d_in[1];   // [C] f32
    const float* mu = (const float*)d_in[2];   // scalar (1-elem array)
    float* out = (float*)d_out;

    float* Spart = (float*)d_ws;                       // 32*64*784*4 = 6.4 MB
    float* S     = Spart + (size_t)NCHUNK * ND * HWD;  // 64*784 = 200 KB

    dim3 g1(NCHUNK, ND);
    // MEASUREMENT: pass1 launched twice (idempotent). Delta vs 98.85us
    // baseline = one L3-warm pass1 duration.
    pass1_kernel<<<g1, 256, 0, stream>>>(x, w, mu, Spart);
    pass1_kernel<<<g1, 256, 0, stream>>>(x, w, mu, Spart);

    // Reduce: 50176 outputs
    reduce_kernel<<<ND * HWD / 256, 256, 0, stream>>>(Spart, S);

    // Mult: 3136 blocks x 256 threads, fixed (n,p4) per thread
    mult_kernel<<<3136, 256, 0, stream>>>(x, S, out);
}

// Round 16
// 109.863 us; speedup vs baseline: 1.1907x; 1.1907x over previous
//
#include <hip/hip_runtime.h>

// Problem shape (fixed by reference): N=64, C=1024, H=W=28 -> HW=784
#define HWD 784
#define Q4  196            // HWD/4 float4 slots per channel row
#define CD  1024
#define ND  64

#define CHPB 16            // channels per pass1 block (LDS-staged tile)
#define NCHUNK (CD / CHPB) // 64 partial chunks

typedef float f32x4 __attribute__((ext_vector_type(4)));
typedef const __attribute__((address_space(1))) void* gas_t;
typedef __attribute__((address_space(3))) void* las_t;

__device__ __forceinline__ float4 cam4(float4 v, float wc) {
    float4 r;
    r.x = fmaxf(v.x * wc, 0.f);
    r.y = fmaxf(v.y * wc, 0.f);
    r.z = fmaxf(v.z * wc, 0.f);
    r.w = fmaxf(v.w * wc, 0.f);
    return r;
}
__device__ __forceinline__ float max4(float4 v) {
    return fmaxf(fmaxf(v.x, v.y), fmaxf(v.z, v.w));
}
__device__ __forceinline__ void accdrop(float4& a, float4 c, float thr) {
    a.x += (c.x > thr) ? 0.f : c.x;
    a.y += (c.y > thr) ? 0.f : c.y;
    a.z += (c.z > thr) ? 0.f : c.z;
    a.w += (c.w > thr) ? 0.f : c.w;
}

// ---------------------------------------------------------------------------
// Pass 1 v7: global_load_lds staging to break the MLP cap.
// Block = (chunk of 16 channels, n), 256 threads = 4 waves, 49KB LDS tile.
// Stage: each wave issues 4 rows x (3 full + 1 tail) width-16 global_load_lds
// (no VGPR landing zone -> ~49KB in flight per block, 3 blocks/CU ~147KB).
// One barrier (drains vmcnt). Compute: per-channel max -> thr -> dropped-sum
// from LDS (2-way bank aliasing = free). Combine reuses the LDS tile.
// ---------------------------------------------------------------------------
__global__ void __launch_bounds__(256) pass1_kernel(const float* __restrict__ x,
                                                    const float* __restrict__ w,
                                                    const float* __restrict__ mu_p,
                                                    float* __restrict__ Spart) {
    __shared__ float lds[CHPB][HWD];   // 50176 B

    const int t = threadIdx.x;
    const int wave = t >> 6;
    const int lane = t & 63;
    const int n = blockIdx.x & (ND - 1);
    const int chunk = blockIdx.x >> 6;
    const int cbase = chunk * CHPB;
    const float mu = mu_p[0];

    // ---- stage: wave w stages rows 4w..4w+3 (784 floats = 3*256 + 16) ----
    const float* xbase = x + ((size_t)n * CD + cbase) * HWD;
    #pragma unroll
    for (int j = 0; j < 4; ++j) {
        const int r = wave * 4 + j;
        const float* rowg = xbase + (size_t)r * HWD;
        #pragma unroll
        for (int k = 0; k < 3; ++k) {
            __builtin_amdgcn_global_load_lds((gas_t)(rowg + k * 256 + lane * 4),
                                             (las_t)&lds[r][k * 256], 16, 0, 0);
        }
        if (lane < 4) {
            __builtin_amdgcn_global_load_lds((gas_t)(rowg + 768 + lane * 4),
                                             (las_t)&lds[r][768], 16, 0, 0);
        }
    }
    __syncthreads();   // compiler drains vmcnt before the barrier

    // ---- compute: wave w processes rows 4w..4w+3 ----
    float4 acc0 = {0.f,0.f,0.f,0.f}, acc1 = {0.f,0.f,0.f,0.f};
    float4 acc2 = {0.f,0.f,0.f,0.f}, acc3 = {0.f,0.f,0.f,0.f};

    #pragma unroll
    for (int j = 0; j < 4; ++j) {
        const int r = wave * 4 + j;
        float4 v0 = *reinterpret_cast<const float4*>(&lds[r][4 * lane]);
        float4 v1 = *reinterpret_cast<const float4*>(&lds[r][256 + 4 * lane]);
        float4 v2 = *reinterpret_cast<const float4*>(&lds[r][512 + 4 * lane]);
        float4 v3 = (lane < 4) ? *reinterpret_cast<const float4*>(&lds[r][768 + 4 * lane])
                               : float4{0.f,0.f,0.f,0.f};
        const float wc = w[cbase + r];

        v0 = cam4(v0, wc); v1 = cam4(v1, wc); v2 = cam4(v2, wc); v3 = cam4(v3, wc);

        float m = fmaxf(fmaxf(max4(v0), max4(v1)), fmaxf(max4(v2), max4(v3)));
        #pragma unroll
        for (int off = 32; off > 0; off >>= 1)
            m = fmaxf(m, __shfl_xor(m, off, 64));
        const float thr = m * mu;

        accdrop(acc0, v0, thr);
        accdrop(acc1, v1, thr);
        accdrop(acc2, v2, thr);
        accdrop(acc3, v3, thr);      // zeros for lane >= 4: harmless
    }

    __syncthreads();   // all LDS reads done before tile reuse

    // ---- combine: reuse the staging tile (4 x 788-float partial rows) ----
    float* f = &lds[0][0];
    float4* drp4 = reinterpret_cast<float4*>(f);
    drp4[wave * 197 + lane]       = acc0;
    drp4[wave * 197 + 64 + lane]  = acc1;
    drp4[wave * 197 + 128 + lane] = acc2;
    if (lane < 4) drp4[wave * 197 + 192 + lane] = acc3;
    __syncthreads();

    float* sp = Spart + ((size_t)chunk * ND + n) * HWD;
    for (int p = t; p < HWD; p += 256)
        sp[p] = f[p] + f[788 + p] + f[2 * 788 + p] + f[3 * 788 + p];
}

// ---------------------------------------------------------------------------
// Reduce: S[n,p] = sum over 64 chunks of Spart[chunk][n][p]. Coalesced;
// Spart (12.8MB) is L2-resident.
// ---------------------------------------------------------------------------
__global__ void __launch_bounds__(256) reduce_kernel(const float* __restrict__ Spart,
                                                     float* __restrict__ S) {
    const int j = blockIdx.x * 256 + threadIdx.x;   // 0 .. 50175
    float s = 0.f;
    #pragma unroll 8
    for (int ch = 0; ch < NCHUNK; ++ch)
        s += Spart[(size_t)ch * ND * HWD + j];
    S[j] = s;
}

// ---------------------------------------------------------------------------
// Mult (unchanged, ~45us): fixed (n,p4) per thread, S loaded once, 1KB/wave
// linear segments, NT stores so the out stream doesn't evict x from L3.
// ---------------------------------------------------------------------------
__global__ void __launch_bounds__(256) mult_kernel(const float* __restrict__ x,
                                                   const float* __restrict__ S,
                                                   float* __restrict__ out) {
    const float4* x4 = reinterpret_cast<const float4*>(x);
    const float4* S4 = reinterpret_cast<const float4*>(S);

    const int tid = blockIdx.x * 256 + threadIdx.x;   // 0 .. 802815
    const int n   = tid / (64 * Q4);                  // 0..63
    const int rem = tid - n * (64 * Q4);
    const int c0  = rem / Q4;                         // 0..63
    const int p4  = rem - c0 * Q4;                    // 0..195

    const float4 sv = S4[n * Q4 + p4];                // one S load, reused 16x
    size_t i4 = ((size_t)(n * CD + c0)) * Q4 + p4;

    #pragma unroll 8
    for (int k = 0; k < 16; ++k, i4 += (size_t)64 * Q4) {
        float4 xv = x4[i4];
        float4 o;
        o.x = xv.x * sv.x;
        o.y = xv.y * sv.y;
        o.z = xv.z * sv.z;
        o.w = xv.w * sv.w;
        __builtin_nontemporal_store(*reinterpret_cast<const f32x4*>(&o),
                                    reinterpret_cast<f32x4*>(out) + i4);
    }
}

extern "C" void kernel_launch(void* const* d_in, const int* in_sizes, int n_in,
                              void* d_out, int out_size, void* d_ws, size_t ws_size,
                              hipStream_t stream) {
    const float* x  = (const float*)d_in[0];   // [N, C, H, W] f32
    const float* w  = (const float*)d_in[1];   // [C] f32
    const float* mu = (const float*)d_in[2];   // scalar (1-elem array)
    float* out = (float*)d_out;

    float* Spart = (float*)d_ws;                       // 64*64*784*4 = 12.8 MB
    float* S     = Spart + (size_t)NCHUNK * ND * HWD;  // 64*784 = 200 KB

    // Pass 1: 64 chunks x 64 samples = 4096 blocks, 256 threads, 49KB LDS
    pass1_kernel<<<NCHUNK * ND, 256, 0, stream>>>(x, w, mu, Spart);

    // Reduce: 50176 outputs
    reduce_kernel<<<ND * HWD / 256, 256, 0, stream>>>(Spart, S);

    // Mult: 3136 blocks x 256 threads, fixed (n,p4) per thread
    mult_kernel<<<3136, 256, 0, stream>>>(x, S, out);
}

// Round 18
// 108.328 us; speedup vs baseline: 1.2076x; 1.0142x over previous
//
#include <hip/hip_runtime.h>

// Problem shape (fixed by reference): N=64, C=1024, H=W=28 -> HW=784
#define HWD 784
#define Q4  196            // HWD/4 float4 slots per channel row
#define CD  1024
#define ND  64

#define CHPB 32            // channels per pass1 block (4 waves x 8)
#define NCHUNK (CD / CHPB) // 32 partial chunks

typedef float f32x4 __attribute__((ext_vector_type(4)));

__device__ __forceinline__ float4 cam4(float4 v, float wc) {
    float4 r;
    r.x = fmaxf(v.x * wc, 0.f);
    r.y = fmaxf(v.y * wc, 0.f);
    r.z = fmaxf(v.z * wc, 0.f);
    r.w = fmaxf(v.w * wc, 0.f);
    return r;
}
__device__ __forceinline__ float max4(float4 v) {
    return fmaxf(fmaxf(v.x, v.y), fmaxf(v.z, v.w));
}
__device__ __forceinline__ void accdrop(float4& a, float4 c, float thr) {
    a.x += (c.x > thr) ? 0.f : c.x;
    a.y += (c.y > thr) ? 0.f : c.y;
    a.z += (c.z > thr) ? 0.f : c.z;
    a.w += (c.w > thr) ? 0.f : c.w;
}

// ---------------------------------------------------------------------------
// Pass 1 (round-14 v6, known-good): block = (chunk of 32 channels, n),
// 256 threads = 4 waves, 8 channels/wave with a 2-deep software pipeline
// (channel j+1's 4 float4 loads issue before channel j's shfl-butterfly).
// Dropped-sum accumulated in registers; LDS combine; coalesced Spart store.
// ---------------------------------------------------------------------------
__global__ void __launch_bounds__(256) pass1_kernel(const float* __restrict__ x,
                                                    const float* __restrict__ w,
                                                    const float* __restrict__ mu_p,
                                                    float* __restrict__ Spart) {
    __shared__ float4 drp[4][197];   // wave stride 197*4 = 788 floats

    const int t = threadIdx.x;
    const int wave = t >> 6;
    const int lane = t & 63;
    const int n = blockIdx.y;
    const int cbase = blockIdx.x * CHPB + wave * 8;
    const float mu = mu_p[0];

    const float4* rows = reinterpret_cast<const float4*>(x + ((size_t)n * CD + cbase) * HWD);

    float4 acc0 = {0.f,0.f,0.f,0.f}, acc1 = {0.f,0.f,0.f,0.f};
    float4 acc2 = {0.f,0.f,0.f,0.f}, acc3 = {0.f,0.f,0.f,0.f};

    // prologue: load channel 0
    float4 v0 = rows[lane];
    float4 v1 = rows[lane + 64];
    float4 v2 = rows[lane + 128];
    float4 v3 = (lane < 4) ? rows[192 + lane] : float4{0.f,0.f,0.f,0.f};

    #pragma unroll 2
    for (int j = 0; j < 8; ++j) {
        // prefetch channel j+1 (independent of this iteration's compute)
        float4 p0 = v0, p1 = v1, p2 = v2, p3 = v3;
        if (j < 7) {
            const float4* rn = rows + (j + 1) * Q4;
            p0 = rn[lane];
            p1 = rn[lane + 64];
            p2 = rn[lane + 128];
            if (lane < 4) p3 = rn[192 + lane];
        }

        const float wc = w[cbase + j];
        float4 c0 = cam4(v0, wc), c1 = cam4(v1, wc);
        float4 c2 = cam4(v2, wc), c3 = cam4(v3, wc);

        float m = fmaxf(fmaxf(max4(c0), max4(c1)), fmaxf(max4(c2), max4(c3)));
        #pragma unroll
        for (int off = 32; off > 0; off >>= 1)
            m = fmaxf(m, __shfl_xor(m, off, 64));
        const float thr = m * mu;

        accdrop(acc0, c0, thr);
        accdrop(acc1, c1, thr);
        accdrop(acc2, c2, thr);
        accdrop(acc3, c3, thr);      // zeros for lane >= 4: harmless

        v0 = p0; v1 = p1; v2 = p2; v3 = p3;
    }

    drp[wave][lane]       = acc0;
    drp[wave][64 + lane]  = acc1;
    drp[wave][128 + lane] = acc2;
    if (lane < 4) drp[wave][192 + lane] = acc3;
    __syncthreads();

    const float* f = reinterpret_cast<const float*>(&drp[0][0]);
    float* sp = Spart + ((size_t)blockIdx.x * ND + n) * HWD;
    for (int p = t; p < HWD; p += 256)
        sp[p] = f[p] + f[788 + p] + f[2 * 788 + p] + f[3 * 788 + p];
}

// ---------------------------------------------------------------------------
// Mult with folded reduce: block b -> (n = b/49, piece = b%49).
// Prologue: 256 threads sum the 32 Spart partials for all 784 positions of
// sample n (ch-ascending -> bitwise identical to the old reduce kernel) into
// a 3KB LDS row; ~25KB of L2/L3-hot reads per block, overlapped across
// blocks. One barrier. Main loop: exact round-11/14 linear mult — fixed
// (n,p4) per thread, 16 channel iterations, 1KB/wave linear segments,
// NT stores so the out stream doesn't evict x from L3.
// ---------------------------------------------------------------------------
__global__ void __launch_bounds__(256) mult_kernel(const float* __restrict__ x,
                                                   const float* __restrict__ Spart,
                                                   float* __restrict__ out) {
    __shared__ float S_row[HWD];

    const int t = threadIdx.x;
    const int b = blockIdx.x;
    const int n = b / 49;
    const int piece = b - n * 49;

    // ---- folded reduce: S_row[p] = sum_ch Spart[ch][n][p] ----
    #pragma unroll
    for (int rep = 0; rep < 3; ++rep) {
        const int p = rep * 256 + t;
        float s = 0.f;
        #pragma unroll 8
        for (int ch = 0; ch < NCHUNK; ++ch)
            s += Spart[((size_t)ch * ND + n) * HWD + p];
        S_row[p] = s;
    }
    if (t < 16) {
        const int p = 768 + t;
        float s = 0.f;
        #pragma unroll 8
        for (int ch = 0; ch < NCHUNK; ++ch)
            s += Spart[((size_t)ch * ND + n) * HWD + p];
        S_row[p] = s;
    }
    __syncthreads();

    // ---- linear mult (unchanged access pattern) ----
    const float4* x4 = reinterpret_cast<const float4*>(x);
    const int rem = piece * 256 + t;          // 0 .. 12543
    const int c0  = rem / Q4;                 // 0..63
    const int p4  = rem - c0 * Q4;            // 0..195

    const float4 sv = *reinterpret_cast<const float4*>(&S_row[4 * p4]);
    size_t i4 = ((size_t)(n * CD + c0)) * Q4 + p4;

    #pragma unroll 8
    for (int k = 0; k < 16; ++k, i4 += (size_t)64 * Q4) {
        float4 xv = x4[i4];
        float4 o;
        o.x = xv.x * sv.x;
        o.y = xv.y * sv.y;
        o.z = xv.z * sv.z;
        o.w = xv.w * sv.w;
        __builtin_nontemporal_store(*reinterpret_cast<const f32x4*>(&o),
                                    reinterpret_cast<f32x4*>(out) + i4);
    }
}

extern "C" void kernel_launch(void* const* d_in, const int* in_sizes, int n_in,
                              void* d_out, int out_size, void* d_ws, size_t ws_size,
                              hipStream_t stream) {
    const float* x  = (const float*)d_in[0];   // [N, C, H, W] f32
    const float* w  = (const float*)d_in[1];   // [C] f32
    const float* mu = (const float*)d_in[2];   // scalar (1-elem array)
    float* out = (float*)d_out;

    float* Spart = (float*)d_ws;               // 32*64*784*4 = 6.4 MB scratch

    // Pass 1: 32 chunks x 64 samples, 256 threads (4 waves x 8 channels)
    dim3 g1(NCHUNK, ND);
    pass1_kernel<<<g1, 256, 0, stream>>>(x, w, mu, Spart);

    // Mult (with folded reduce): 3136 blocks x 256 threads
    mult_kernel<<<ND * 49, 256, 0, stream>>>(x, Spart, out);
}

// Round 19
// 102.166 us; speedup vs baseline: 1.2804x; 1.0603x over previous
//
#include <hip/hip_runtime.h>

// Problem shape (fixed by reference): N=64, C=1024, H=W=28 -> HW=784
#define HWD 784
#define Q4  196            // HWD/4 float4 slots per channel row
#define CD  1024
#define ND  64

#define CPW 4              // channels per wave  (churn experiment: was 8)
#define CHPB (4 * CPW)     // 16 channels per block (4 waves)
#define NCHUNK (CD / CHPB) // 64 partial chunks

typedef float f32x4 __attribute__((ext_vector_type(4)));

__device__ __forceinline__ float4 cam4(float4 v, float wc) {
    float4 r;
    r.x = fmaxf(v.x * wc, 0.f);
    r.y = fmaxf(v.y * wc, 0.f);
    r.z = fmaxf(v.z * wc, 0.f);
    r.w = fmaxf(v.w * wc, 0.f);
    return r;
}
__device__ __forceinline__ float max4(float4 v) {
    return fmaxf(fmaxf(v.x, v.y), fmaxf(v.z, v.w));
}
__device__ __forceinline__ void accdrop(float4& a, float4 c, float thr) {
    a.x += (c.x > thr) ? 0.f : c.x;
    a.y += (c.y > thr) ? 0.f : c.y;
    a.z += (c.z > thr) ? 0.f : c.z;
    a.w += (c.w > thr) ? 0.f : c.w;
}

// ---------------------------------------------------------------------------
// Pass 1 v8 (churn experiment): wave = 4 channels (was 8) -> 4096 blocks,
// 16384 waves = 2x device residency, so finished waves hand their SIMD slot
// to queued ones (thr_kernel-style churn). Same 2-deep software pipeline,
// same 256-thread block, same LDS combine, Spart chunk count 32 -> 64.
// ---------------------------------------------------------------------------
__global__ void __launch_bounds__(256) pass1_kernel(const float* __restrict__ x,
                                                    const float* __restrict__ w,
                                                    const float* __restrict__ mu_p,
                                                    float* __restrict__ Spart) {
    __shared__ float4 drp[4][197];   // wave stride 197*4 = 788 floats

    const int t = threadIdx.x;
    const int wave = t >> 6;
    const int lane = t & 63;
    const int n = blockIdx.y;
    const int cbase = blockIdx.x * CHPB + wave * CPW;
    const float mu = mu_p[0];

    const float4* rows = reinterpret_cast<const float4*>(x + ((size_t)n * CD + cbase) * HWD);

    float4 acc0 = {0.f,0.f,0.f,0.f}, acc1 = {0.f,0.f,0.f,0.f};
    float4 acc2 = {0.f,0.f,0.f,0.f}, acc3 = {0.f,0.f,0.f,0.f};

    // prologue: load channel 0
    float4 v0 = rows[lane];
    float4 v1 = rows[lane + 64];
    float4 v2 = rows[lane + 128];
    float4 v3 = (lane < 4) ? rows[192 + lane] : float4{0.f,0.f,0.f,0.f};

    #pragma unroll 2
    for (int j = 0; j < CPW; ++j) {
        // prefetch channel j+1 (independent of this iteration's compute)
        float4 p0 = v0, p1 = v1, p2 = v2, p3 = v3;
        if (j < CPW - 1) {
            const float4* rn = rows + (j + 1) * Q4;
            p0 = rn[lane];
            p1 = rn[lane + 64];
            p2 = rn[lane + 128];
            if (lane < 4) p3 = rn[192 + lane];
        }

        const float wc = w[cbase + j];
        float4 c0 = cam4(v0, wc), c1 = cam4(v1, wc);
        float4 c2 = cam4(v2, wc), c3 = cam4(v3, wc);

        float m = fmaxf(fmaxf(max4(c0), max4(c1)), fmaxf(max4(c2), max4(c3)));
        #pragma unroll
        for (int off = 32; off > 0; off >>= 1)
            m = fmaxf(m, __shfl_xor(m, off, 64));
        const float thr = m * mu;

        accdrop(acc0, c0, thr);
        accdrop(acc1, c1, thr);
        accdrop(acc2, c2, thr);
        accdrop(acc3, c3, thr);      // zeros for lane >= 4: harmless

        v0 = p0; v1 = p1; v2 = p2; v3 = p3;
    }

    drp[wave][lane]       = acc0;
    drp[wave][64 + lane]  = acc1;
    drp[wave][128 + lane] = acc2;
    if (lane < 4) drp[wave][192 + lane] = acc3;
    __syncthreads();

    const float* f = reinterpret_cast<const float*>(&drp[0][0]);
    float* sp = Spart + ((size_t)blockIdx.x * ND + n) * HWD;
    for (int p = t; p < HWD; p += 256)
        sp[p] = f[p] + f[788 + p] + f[2 * 788 + p] + f[3 * 788 + p];
}

// ---------------------------------------------------------------------------
// Reduce: S[n,p] = sum over 64 chunks of Spart[chunk][n][p]. Coalesced;
// Spart (12.8MB) is L2-resident right after pass1.
// ---------------------------------------------------------------------------
__global__ void __launch_bounds__(256) reduce_kernel(const float* __restrict__ Spart,
                                                     float* __restrict__ S) {
    const int j = blockIdx.x * 256 + threadIdx.x;   // 0 .. 50175
    float s = 0.f;
    #pragma unroll 8
    for (int ch = 0; ch < NCHUNK; ++ch)
        s += Spart[(size_t)ch * ND * HWD + j];
    S[j] = s;
}

// ---------------------------------------------------------------------------
// Mult (round-14 known-good, ~45us): fixed (n,p4) per thread, S loaded once
// and reused 16x, 1KB/wave linear segments, NT stores so the out stream
// doesn't evict x from L3 (x is L3-hot after pass1).
// ---------------------------------------------------------------------------
__global__ void __launch_bounds__(256) mult_kernel(const float* __restrict__ x,
                                                   const float* __restrict__ S,
                                                   float* __restrict__ out) {
    const float4* x4 = reinterpret_cast<const float4*>(x);
    const float4* S4 = reinterpret_cast<const float4*>(S);

    const int tid = blockIdx.x * 256 + threadIdx.x;   // 0 .. 802815
    const int n   = tid / (64 * Q4);                  // 0..63
    const int rem = tid - n * (64 * Q4);
    const int c0  = rem / Q4;                         // 0..63
    const int p4  = rem - c0 * Q4;                    // 0..195

    const float4 sv = S4[n * Q4 + p4];                // one S load, reused 16x
    size_t i4 = ((size_t)(n * CD + c0)) * Q4 + p4;

    #pragma unroll 8
    for (int k = 0; k < 16; ++k, i4 += (size_t)64 * Q4) {
        float4 xv = x4[i4];
        float4 o;
        o.x = xv.x * sv.x;
        o.y = xv.y * sv.y;
        o.z = xv.z * sv.z;
        o.w = xv.w * sv.w;
        __builtin_nontemporal_store(*reinterpret_cast<const f32x4*>(&o),
                                    reinterpret_cast<f32x4*>(out) + i4);
    }
}

extern "C" void kernel_launch(void* const* d_in, const int* in_sizes, int n_in,
                              void* d_out, int out_size, void* d_ws, size_t ws_size,
                              hipStream_t stream) {
    const float* x  = (const float*)d_in[0];   // [N, C, H, W] f32
    const float* w  = (const float*)d_in[1];   // [C] f32
    const float* mu = (const float*)d_in[2];   // scalar (1-elem array)
    float* out = (float*)d_out;

    float* Spart = (float*)d_ws;                       // 64*64*784*4 = 12.8 MB
    float* S     = Spart + (size_t)NCHUNK * ND * HWD;  // 64*784 = 200 KB

    // Pass 1: 64 chunks x 64 samples, 256 threads (4 waves x 4 channels)
    dim3 g1(NCHUNK, ND);
    pass1_kernel<<<g1, 256, 0, stream>>>(x, w, mu, Spart);

    // Reduce: 50176 outputs
    reduce_kernel<<<ND * HWD / 256, 256, 0, stream>>>(Spart, S);

    // Mult: 3136 blocks x 256 threads, fixed (n,p4) per thread
    mult_kernel<<<3136, 256, 0, stream>>>(x, S, out);
}